// Round 9
// baseline (436.505 us; speedup 1.0000x reference)
//
#include <hip/hip_runtime.h>
#include <hip/hip_bf16.h>

#define NTOK 4096
#define DEMB 1024
#define NH   8
#define DH   128
#define CWIN 256
#define QKVW 384
#define SCALE 0.08838834764831845f   // 1/sqrt(128)
#define QT 16
#define NCH 34                        // 16-key chunks covering the <=528-wide band

typedef __attribute__((ext_vector_type(8))) short short8;
typedef __attribute__((ext_vector_type(4))) float floatx4;

__device__ __forceinline__ short8 pack8(float4 a, float4 b) {
    union { __hip_bfloat16 h[8]; short8 v; } o;
    o.h[0] = __float2bfloat16(a.x); o.h[1] = __float2bfloat16(a.y);
    o.h[2] = __float2bfloat16(a.z); o.h[3] = __float2bfloat16(a.w);
    o.h[4] = __float2bfloat16(b.x); o.h[5] = __float2bfloat16(b.y);
    o.h[6] = __float2bfloat16(b.z); o.h[7] = __float2bfloat16(b.w);
    return o.v;
}

// ---------------- weight prep (once per call) ----------------
__global__ void pack_wqkv(const float* __restrict__ Wq, const float* __restrict__ Wk,
                          const float* __restrict__ Wvd, __hip_bfloat16* __restrict__ dst) {
    size_t base = ((size_t)blockIdx.x * 256 + threadIdx.x) * 8;
    int k = (int)(base & 1023);
    int rh = (int)(base >> 10);
    int h = rh / QKVW;
    int row = rh - h * QKVW;
    const float* srcs[3] = {Wq, Wk, Wvd};
    const float* s = srcs[row >> 7] + (((size_t)h * DH + (row & 127)) << 10) + k;
    *(short8*)(dst + base) = pack8(*(const float4*)s, *(const float4*)(s + 4));
}

__global__ void pack_wvu(const float* __restrict__ Wvu, __hip_bfloat16* __restrict__ dst) {
    size_t base = ((size_t)blockIdx.x * 256 + threadIdx.x) * 8;
    *(short8*)(dst + base) = pack8(*(const float4*)(Wvu + base), *(const float4*)(Wvu + base + 4));
}

// ---------------- stage 0: e = x (+ bf16 mirror) ---------------------------
__global__ void init_e(const float4* __restrict__ x, float4* __restrict__ e,
                       __hip_bfloat16* __restrict__ ebf) {
    int i = blockIdx.x * 256 + threadIdx.x;
    float4 v = x[i];
    e[i] = v;
    union { __hip_bfloat16 h[4]; uint2 u; } p;
    p.h[0] = __float2bfloat16(v.x); p.h[1] = __float2bfloat16(v.y);
    p.h[2] = __float2bfloat16(v.z); p.h[3] = __float2bfloat16(v.w);
    *(uint2*)(ebf + (size_t)i * 4) = p.u;
}

// ---------------- per-head qkv GEMM: emits Q (scaled), K, V^T --------------
// R8 budget: this GEMM was 8 x 18.3 us = 34% of total at 178 TF. Cause: the
// single-buffer 2-barrier K-loop exposes the full ~500cyc staging latency
// every iteration (~1300 cyc/iter). Fix (T14 async-STAGE + dbuf):
// issue k+1 loads into regs BEFORE the MFMA phase, write them to the OTHER
// LDS buffer after, ONE barrier per iteration. Write-to-other-buffer is
// race-free: reads of buf[cur] in iter i are fenced from iter i+1's writes
// to buf[cur] by the end-of-iter barrier.
__global__ __launch_bounds__(256) void qkv_gemm_mfma(const __hip_bfloat16* __restrict__ A,
                                                     const __hip_bfloat16* __restrict__ B,
                                                     __hip_bfloat16* __restrict__ Qb,
                                                     __hip_bfloat16* __restrict__ Kb,
                                                     __hip_bfloat16* __restrict__ Vtb) {
    constexpr int K = DEMB;
    constexpr int LDK = 40;
    const int c0 = blockIdx.x * 64, r0 = blockIdx.y * 64;
    const int tid = threadIdx.x;
    const int wave = tid >> 6, lane = tid & 63;
    const int wr = (wave >> 1) * 32, wc = (wave & 1) * 32;
    const int frow = lane & 15, kgrp = (lane >> 4) * 8;
    const int quad = lane >> 4;
    const int sr = tid >> 2, sk = (tid & 3) * 8;

    __shared__ __hip_bfloat16 As[2][64 * LDK];
    __shared__ __hip_bfloat16 Bs[2][64 * LDK];

    const __hip_bfloat16* arow = A + (size_t)(r0 + sr) * K + sk;
    const __hip_bfloat16* brow = B + (size_t)(c0 + sr) * K + sk;

    // prologue: stage k0=0 into buf0
    *(short8*)(As[0] + sr * LDK + sk) = *(const short8*)(arow);
    *(short8*)(Bs[0] + sr * LDK + sk) = *(const short8*)(brow);
    __syncthreads();

    floatx4 acc[2][2] = {};
    int cur = 0;

    for (int k0 = 0; k0 < K; k0 += 32) {
        // issue next staging loads early -> latency hides under MFMA below
        short8 a_nx, b_nx;
        const bool more = (k0 + 32 < K);
        if (more) {
            a_nx = *(const short8*)(arow + k0 + 32);
            b_nx = *(const short8*)(brow + k0 + 32);
        }

        short8 a0 = *(const short8*)(As[cur] + (wr + frow) * LDK + kgrp);
        short8 a1 = *(const short8*)(As[cur] + (wr + 16 + frow) * LDK + kgrp);
        short8 b0 = *(const short8*)(Bs[cur] + (wc + frow) * LDK + kgrp);
        short8 b1 = *(const short8*)(Bs[cur] + (wc + 16 + frow) * LDK + kgrp);
        acc[0][0] = __builtin_amdgcn_mfma_f32_16x16x32_bf16(a0, b0, acc[0][0], 0, 0, 0);
        acc[0][1] = __builtin_amdgcn_mfma_f32_16x16x32_bf16(a0, b1, acc[0][1], 0, 0, 0);
        acc[1][0] = __builtin_amdgcn_mfma_f32_16x16x32_bf16(a1, b0, acc[1][0], 0, 0, 0);
        acc[1][1] = __builtin_amdgcn_mfma_f32_16x16x32_bf16(a1, b1, acc[1][1], 0, 0, 0);

        if (more) {
            *(short8*)(As[cur ^ 1] + sr * LDK + sk) = a_nx;
            *(short8*)(Bs[cur ^ 1] + sr * LDK + sk) = b_nx;
        }
        __syncthreads();              // one barrier/iter: nxt visible + cur free
        cur ^= 1;
    }

    #pragma unroll
    for (int i = 0; i < 2; i++)
        #pragma unroll
        for (int j = 0; j < 2; j++) {
            int col = c0 + wc + j * 16 + frow;
            int row0 = r0 + wr + i * 16 + quad * 4;
            if (col < DH) {
                #pragma unroll
                for (int r = 0; r < 4; r++)
                    Qb[(size_t)(row0 + r) * DH + col] = __float2bfloat16(acc[i][j][r] * SCALE);
            } else if (col < 2 * DH) {
                #pragma unroll
                for (int r = 0; r < 4; r++)
                    Kb[(size_t)(row0 + r) * DH + col - DH] = __float2bfloat16(acc[i][j][r]);
            } else {
                union { __hip_bfloat16 h[4]; uint2 u; } p;
                #pragma unroll
                for (int r = 0; r < 4; r++) p.h[r] = __float2bfloat16(acc[i][j][r]);
                *(uint2*)(Vtb + (size_t)(col - 2 * DH) * NTOK + row0) = p.u;
            }
        }
}

// ---------------- fused head kernel (attention + out-proj + norm) ----------
// Unchanged from R8 (isolate the qkv change). Linear-layout residual/norm
// via XOR-swizzled f32 LDS bridge; 4 barriers/head; max-subtraction kept
// (R4: mean drift -> |s|>88 by head 7). OOB band-edge fragment reads land
// in adjacent ws buffers: finite bf16, multiplied by p=0.
__global__ __launch_bounds__(512, 2) void attn_head(const __hip_bfloat16* __restrict__ Qb,
                                                    const __hip_bfloat16* __restrict__ Kb,
                                                    const __hip_bfloat16* __restrict__ Vtb,
                                                    __hip_bfloat16* __restrict__ ebf,
                                                    const __hip_bfloat16* __restrict__ Wvu,
                                                    float* __restrict__ e,
                                                    float* __restrict__ out_final) {
    const int tile = ((blockIdx.x & 7) << 5) | (blockIdx.x >> 3);
    const int q0 = tile * QT;
    const int tid = threadIdx.x;
    const int wave = tid >> 6, lane = tid & 63;       // wave in [0,8)
    const int fr = lane & 15, kg = (lane >> 4) * 8;
    const int quad = lane >> 4;
    const bool last = (out_final != nullptr);

    __shared__ alignas(16) __hip_bfloat16 Us[QT][DH + 8];      // u rows (attn out)
    __shared__ alignas(16) __hip_bfloat16 Pb[QT][NCH * 16 + 8];
    __shared__ alignas(16) float Dls[QT * DEMB];               // delta bridge (swizzled)
    __shared__ float statsA[QT][8];
    __shared__ float statsB[QT][8];

    // ---- e prefetch in LINEAR mapping: thread owns row=tid>>5,
    // cols {j*128 + (tid&31)*4 .. +3}. Written by the SAME tile last launch.
    const int lrow = tid >> 5, l32 = tid & 31;
    floatx4 ev4[8];
    {
        const float* erow = e + (size_t)(q0 + lrow) * DEMB + l32 * 4;
        #pragma unroll
        for (int j = 0; j < 8; j++)
            ev4[j] = *(const floatx4*)(erow + j * 128);
    }

    // ---- Q fragments straight from L2 (pre-scaled) ------------------------
    short8 af[4];
    #pragma unroll
    for (int kc = 0; kc < 4; kc++)
        af[kc] = *(const short8*)(Qb + (size_t)(q0 + fr) * DH + kc * 32 + kg);

    const int kstart = max(q0 - CWIN, 0);
    const int kend   = min(q0 + QT - 1 + CWIN + 1, NTOK);
    const int nch = (wave < 2) ? 5 : 4;   // chunks ch = wave + 8t, ch < 34

    // ---- scores: preload K fragments, then MFMA ---------------------------
    short8 kf[5][4];
    #pragma unroll
    for (int t = 0; t < 5; t++) {
        if (t >= nch) break;
        const __hip_bfloat16* krow = Kb + (size_t)(kstart + (wave + 8 * t) * 16 + fr) * DH;
        #pragma unroll
        for (int kc = 0; kc < 4; kc++)
            kf[t][kc] = *(const short8*)(krow + kc * 32 + kg);
    }
    floatx4 sreg[5];
    #pragma unroll
    for (int t = 0; t < 5; t++) {
        if (t >= nch) break;
        floatx4 s = {};
        #pragma unroll
        for (int kc = 0; kc < 4; kc++)
            s = __builtin_amdgcn_mfma_f32_16x16x32_bf16(af[kc], kf[t][kc], s, 0, 0, 0);
        sreg[t] = s;
    }

    // ---- band mask + per-row max ------------------------------------------
    float pmax[4] = {-1e30f, -1e30f, -1e30f, -1e30f};
    #pragma unroll
    for (int t = 0; t < 5; t++) {
        if (t >= nch) break;
        int tcol = kstart + (wave + 8 * t) * 16 + fr;
        #pragma unroll
        for (int r = 0; r < 4; r++) {
            int qg = q0 + quad * 4 + r;
            bool ok = (tcol < kend) && (tcol >= qg - CWIN) && (tcol < qg + CWIN);
            float v = ok ? sreg[t][r] : -1e30f;
            sreg[t][r] = v;
            pmax[r] = fmaxf(pmax[r], v);
        }
    }
    #pragma unroll
    for (int mm = 1; mm <= 8; mm <<= 1)
        #pragma unroll
        for (int r = 0; r < 4; r++) pmax[r] = fmaxf(pmax[r], __shfl_xor(pmax[r], mm, 64));
    if (fr == 0)
        #pragma unroll
        for (int r = 0; r < 4; r++) statsA[quad * 4 + r][wave] = pmax[r];
    __syncthreads();                                   // bar1: row maxes

    float M[4];
    #pragma unroll
    for (int r = 0; r < 4; r++) {
        int row = quad * 4 + r;
        float m = statsA[row][0];
        #pragma unroll
        for (int w = 1; w < 8; w++) m = fmaxf(m, statsA[row][w]);
        M[r] = m;
    }

    // ---- exp(s - M) -> Pb (A-layout), row sums ----------------------------
    float psum[4] = {};
    #pragma unroll
    for (int t = 0; t < 5; t++) {
        if (t >= nch) break;
        int colb = (wave + 8 * t) * 16 + fr;
        #pragma unroll
        for (int r = 0; r < 4; r++) {
            float p = __expf(sreg[t][r] - M[r]);
            psum[r] += p;
            Pb[quad * 4 + r][colb] = __float2bfloat16(p);
        }
    }
    #pragma unroll
    for (int mm = 1; mm <= 8; mm <<= 1)
        #pragma unroll
        for (int r = 0; r < 4; r++) psum[r] += __shfl_xor(psum[r], mm, 64);
    if (fr == 0)
        #pragma unroll
        for (int r = 0; r < 4; r++) statsB[quad * 4 + r][wave] = psum[r];
    __syncthreads();                                   // bar2: Pb + sums

    float linv[4];
    #pragma unroll
    for (int r = 0; r < 4; r++) {
        int row = quad * 4 + r;
        float s = statsB[row][0];
        #pragma unroll
        for (int w = 1; w < 8; w++) s += statsB[row][w];
        linv[r] = 1.0f / s;
    }

    // ---- PV: wave owns dims [16w,16w+16); 8-deep Vt fragment ring ---------
    {
        const __hip_bfloat16* vbase = Vtb + (size_t)(wave * 16 + fr) * NTOK + kstart + kg;
        short8 vf[8];
        #pragma unroll
        for (int i = 0; i < 8; i++) vf[i] = *(const short8*)(vbase + i * 32);
        floatx4 Of = {};
        #pragma unroll
        for (int kc = 0; kc < NCH / 2; kc++) {
            short8 pf = *(const short8*)&Pb[fr][kc * 32 + kg];
            short8 v = vf[kc & 7];
            if (kc + 8 < NCH / 2) vf[kc & 7] = *(const short8*)(vbase + (kc + 8) * 32);
            Of = __builtin_amdgcn_mfma_f32_16x16x32_bf16(pf, v, Of, 0, 0, 0);
        }
        int col = wave * 16 + fr;
        #pragma unroll
        for (int r = 0; r < 4; r++)
            Us[quad * 4 + r][col] = __float2bfloat16(Of[r] * linv[r]);
    }
    __syncthreads();                                   // bar3: u rows ready
    short8 af2[4];
    #pragma unroll
    for (int kc = 0; kc < 4; kc++) af2[kc] = *(const short8*)&Us[fr][kc * 32 + kg];

    // ---- out-proj: wave owns cols [128w,128w+128); 3-deep Wvu ring --------
    floatx4 accd[8] = {};
    {
        short8 wf[3][4];
        #pragma unroll
        for (int g = 0; g < 2; g++) {
            const __hip_bfloat16* wrow = Wvu + ((size_t)(wave * 128 + g * 16 + fr) << 7);
            #pragma unroll
            for (int kc = 0; kc < 4; kc++) wf[g][kc] = *(const short8*)(wrow + kc * 32 + kg);
        }
        #pragma unroll
        for (int n0 = 0; n0 < 8; n0++) {
            int cur = n0 % 3;
            if (n0 + 2 < 8) {
                int nx = (n0 + 2) % 3;
                const __hip_bfloat16* wrow = Wvu + ((size_t)(wave * 128 + (n0 + 2) * 16 + fr) << 7);
                #pragma unroll
                for (int kc = 0; kc < 4; kc++) wf[nx][kc] = *(const short8*)(wrow + kc * 32 + kg);
            }
            #pragma unroll
            for (int kc = 0; kc < 4; kc++)
                accd[n0] = __builtin_amdgcn_mfma_f32_16x16x32_bf16(af2[kc], wf[cur][kc],
                                                                  accd[n0], 0, 0, 0);
        }
    }

    // ---- delta -> LDS bridge (MFMA layout writer, XOR-swizzled 16B chunks)
    #pragma unroll
    for (int n0 = 0; n0 < 8; n0++) {
        int c_w = wave * 32 + n0 * 4 + (fr >> 2);          // 16B chunk idx in row
        int pc  = c_w ^ ((c_w >> 3) & 7);                  // swizzle (involution)
        #pragma unroll
        for (int r = 0; r < 4; r++)
            Dls[((quad * 4 + r) << 10) + (pc << 2) + (fr & 3)] = accd[n0][r];
    }
    __syncthreads();                                   // bar4: delta ready

    // ---- residual + double-norm in LINEAR mapping -------------------------
    floatx4 dv4[8];
    float s1 = 0.0f, s2 = 0.0f;
    #pragma unroll
    for (int j = 0; j < 8; j++) {
        int c_r = j * 32 + l32;
        int pc  = c_r ^ ((c_r >> 3) & 7);
        floatx4 d = *(const floatx4*)&Dls[(lrow << 10) + (pc << 2)];
        dv4[j] = d;
        #pragma unroll
        for (int k = 0; k < 4; k++) {
            float od = ev4[j][k] + d[k];
            s1 += od; s2 += od * od;
        }
    }
    #pragma unroll
    for (int mm = 1; mm <= 16; mm <<= 1) {             // 32-lane row reduction
        s1 += __shfl_xor(s1, mm, 64);
        s2 += __shfl_xor(s2, mm, 64);
    }
    float m0 = s1 * (1.0f / DEMB);
    float iv = 1.0f / m0;
    float m  = m0 * iv;                                // mean(out/m0) ~ 1
    float st = s1 * iv;
    float var = (s2 * iv * iv - st * st * (1.0f / DEMB)) * (1.0f / (DEMB - 1));
    float isd = rsqrtf(var);

    // ---- final residual+norm; vectorized stores ---------------------------
    {
        float* eout = e + (size_t)(q0 + lrow) * DEMB + l32 * 4;
        __hip_bfloat16* ebout = ebf + (size_t)(q0 + lrow) * DEMB + l32 * 4;
        float* fout = last ? (out_final + (size_t)(q0 + lrow) * DEMB + l32 * 4) : nullptr;
        #pragma unroll
        for (int j = 0; j < 8; j++) {
            floatx4 res;
            #pragma unroll
            for (int k = 0; k < 4; k++) {
                float evv = ev4[j][k];
                float t = (evv + dv4[j][k]) * iv;
                res[k] = evv + (t - m) * isd + m;
            }
            if (last) {
                floatx4 ro = {res[0] * 0.125f, res[1] * 0.125f, res[2] * 0.125f, res[3] * 0.125f};
                *(floatx4*)(fout + j * 128) = ro;
            } else {
                *(floatx4*)(eout + j * 128) = res;
                union { __hip_bfloat16 h[4]; uint2 u; } p;
                #pragma unroll
                for (int k = 0; k < 4; k++) p.h[k] = __float2bfloat16(res[k]);
                *(uint2*)(ebout + j * 128) = p.u;
            }
        }
    }
}

extern "C" void kernel_launch(void* const* d_in, const int* in_sizes, int n_in,
                              void* d_out, int out_size, void* d_ws, size_t ws_size,
                              hipStream_t stream) {
    const float* x   = (const float*)d_in[0];
    const float* Wq  = (const float*)d_in[1];
    const float* Wk  = (const float*)d_in[2];
    const float* Wvd = (const float*)d_in[3];
    const float* Wvu = (const float*)d_in[4];

    char* ws = (char*)d_ws;
    float* e = (float*)ws;                                              // 16 MB
    __hip_bfloat16* ebf   = (__hip_bfloat16*)(ws + (16u << 20));        //  8 MB bf16 mirror of e
    __hip_bfloat16* Qb[2] = {(__hip_bfloat16*)(ws + (24u << 20)),
                             (__hip_bfloat16*)(ws + (27u << 20))};      //  1 MB each
    __hip_bfloat16* Kb[2] = {(__hip_bfloat16*)(ws + (25u << 20)),
                             (__hip_bfloat16*)(ws + (28u << 20))};
    __hip_bfloat16* Vt[2] = {(__hip_bfloat16*)(ws + (26u << 20)),
                             (__hip_bfloat16*)(ws + (29u << 20))};
    __hip_bfloat16* wqkvb = (__hip_bfloat16*)(ws + (30u << 20));        //  6 MB
    __hip_bfloat16* wvub  = (__hip_bfloat16*)(ws + (36u << 20));        //  2 MB  -> 38 MB

    pack_wqkv<<<NH * QKVW * DEMB / 8 / 256, 256, 0, stream>>>(Wq, Wk, Wvd, wqkvb);
    pack_wvu<<<NH * DEMB * DH / 8 / 256, 256, 0, stream>>>(Wvu, wvub);
    init_e<<<NTOK * DEMB / 4 / 256, 256, 0, stream>>>((const float4*)x, (float4*)e, ebf);

    // head-0 QKV from the x mirror
    qkv_gemm_mfma<<<dim3(QKVW / 64, NTOK / 64), 256, 0, stream>>>(
        ebf, wqkvb, Qb[0], Kb[0], Vt[0]);

    for (int h = 0; h < NH; h++) {
        int cur = h & 1, nxt = 1 - cur;
        attn_head<<<NTOK / QT, 512, 0, stream>>>(
            Qb[cur], Kb[cur], Vt[cur],
            ebf, wvub + (size_t)h * DEMB * DH, e,
            (h == NH - 1) ? (float*)d_out : nullptr);
        if (h + 1 < NH)   // de-fused next-head QKV (reads ebf written above)
            qkv_gemm_mfma<<<dim3(QKVW / 64, NTOK / 64), 256, 0, stream>>>(
                ebf, wqkvb + (size_t)(h + 1) * QKVW * DEMB,
                Qb[nxt], Kb[nxt], Vt[nxt]);
    }
}

// Round 11
// 416.537 us; speedup vs baseline: 1.0479x; 1.0479x over previous
//
#include <hip/hip_runtime.h>
#include <hip/hip_bf16.h>

#define NTOK 4096
#define DEMB 1024
#define NH   8
#define DH   128
#define CWIN 256
#define QKVW 384
#define SCALE 0.08838834764831845f   // 1/sqrt(128)
#define QT 16
#define NCH 34                        // 16-key chunks covering the <=528-wide band

typedef __attribute__((ext_vector_type(8))) short short8;
typedef __attribute__((ext_vector_type(4))) short short4v;
typedef __attribute__((ext_vector_type(4))) float floatx4;

__device__ __forceinline__ short8 pack8(float4 a, float4 b) {
    union { __hip_bfloat16 h[8]; short8 v; } o;
    o.h[0] = __float2bfloat16(a.x); o.h[1] = __float2bfloat16(a.y);
    o.h[2] = __float2bfloat16(a.z); o.h[3] = __float2bfloat16(a.w);
    o.h[4] = __float2bfloat16(b.x); o.h[5] = __float2bfloat16(b.y);
    o.h[6] = __float2bfloat16(b.z); o.h[7] = __float2bfloat16(b.w);
    return o.v;
}

// ---------------- weight prep (once per call) ----------------
__global__ void pack_wqkv(const float* __restrict__ Wq, const float* __restrict__ Wk,
                          const float* __restrict__ Wvd, __hip_bfloat16* __restrict__ dst) {
    size_t base = ((size_t)blockIdx.x * 256 + threadIdx.x) * 8;
    int k = (int)(base & 1023);
    int rh = (int)(base >> 10);
    int h = rh / QKVW;
    int row = rh - h * QKVW;
    const float* srcs[3] = {Wq, Wk, Wvd};
    const float* s = srcs[row >> 7] + (((size_t)h * DH + (row & 127)) << 10) + k;
    *(short8*)(dst + base) = pack8(*(const float4*)s, *(const float4*)(s + 4));
}

__global__ void pack_wvu(const float* __restrict__ Wvu, __hip_bfloat16* __restrict__ dst) {
    size_t base = ((size_t)blockIdx.x * 256 + threadIdx.x) * 8;
    *(short8*)(dst + base) = pack8(*(const float4*)(Wvu + base), *(const float4*)(Wvu + base + 4));
}

// ---------------- stage 0: e = x (+ bf16 mirror) ---------------------------
__global__ void init_e(const float4* __restrict__ x, float4* __restrict__ e,
                       __hip_bfloat16* __restrict__ ebf) {
    int i = blockIdx.x * 256 + threadIdx.x;
    float4 v = x[i];
    e[i] = v;
    union { __hip_bfloat16 h[4]; uint2 u; } p;
    p.h[0] = __float2bfloat16(v.x); p.h[1] = __float2bfloat16(v.y);
    p.h[2] = __float2bfloat16(v.z); p.h[3] = __float2bfloat16(v.w);
    *(uint2*)(ebf + (size_t)i * 4) = p.u;
}

// ---------------- per-head qkv GEMM: emits Q (scaled), K, V^T --------------
// R9 theory (unmeasured, resubmitted): 1-deep reg-prefetch was neutral
// because per-iter compute (4 MFMA ~80cyc) can't cover ~500cyc load
// latency. The coverable resource is CROSS-BLOCK TLP: old grid 384 = 1.5
// blocks/CU (half the CUs had a single lockstep barrier group -> full
// exposure). Tile 64x64 -> 64x32: grid 768 = 3 blocks/CU, SAME total
// FLOPs/iters. While one block waits at its barrier, two others compute.
// Extra A-panel L2 reads (+48MB/head @ ~35TB/s) ~1.5us.
__global__ __launch_bounds__(256) void qkv_gemm_mfma(const __hip_bfloat16* __restrict__ A,
                                                     const __hip_bfloat16* __restrict__ B,
                                                     __hip_bfloat16* __restrict__ Qb,
                                                     __hip_bfloat16* __restrict__ Kb,
                                                     __hip_bfloat16* __restrict__ Vtb) {
    constexpr int K = DEMB;
    constexpr int LDK = 40;
    const int c0 = blockIdx.x * 32, r0 = blockIdx.y * 64;
    const int tid = threadIdx.x;
    const int wave = tid >> 6, lane = tid & 63;
    const int wr = (wave >> 1) * 32, wc = (wave & 1) * 16;
    const int frow = lane & 15, kgrp = (lane >> 4) * 8;
    const int quad = lane >> 4;
    const int sr = tid >> 2, sk = (tid & 3) * 8;       // A staging: 64 rows x 32
    const int sr2 = tid >> 3, sk2 = (tid & 7) * 4;     // B staging: 32 rows x 32

    __shared__ __hip_bfloat16 As[2][64 * LDK];
    __shared__ __hip_bfloat16 Bs[2][32 * LDK];

    const __hip_bfloat16* arow = A + (size_t)(r0 + sr) * K + sk;
    const __hip_bfloat16* brow = B + (size_t)(c0 + sr2) * K + sk2;

    // prologue: stage k0=0 into buf0
    *(short8*)(As[0] + sr * LDK + sk) = *(const short8*)(arow);
    *(short4v*)(Bs[0] + sr2 * LDK + sk2) = *(const short4v*)(brow);
    __syncthreads();

    floatx4 acc[2] = {};
    int cur = 0;

    for (int k0 = 0; k0 < K; k0 += 32) {
        short8 a_nx; short4v b_nx;
        const bool more = (k0 + 32 < K);
        if (more) {
            a_nx = *(const short8*)(arow + k0 + 32);
            b_nx = *(const short4v*)(brow + k0 + 32);
        }

        short8 a0 = *(const short8*)(As[cur] + (wr + frow) * LDK + kgrp);
        short8 a1 = *(const short8*)(As[cur] + (wr + 16 + frow) * LDK + kgrp);
        short8 b0 = *(const short8*)(Bs[cur] + (wc + frow) * LDK + kgrp);
        acc[0] = __builtin_amdgcn_mfma_f32_16x16x32_bf16(a0, b0, acc[0], 0, 0, 0);
        acc[1] = __builtin_amdgcn_mfma_f32_16x16x32_bf16(a1, b0, acc[1], 0, 0, 0);

        if (more) {
            *(short8*)(As[cur ^ 1] + sr * LDK + sk) = a_nx;
            *(short4v*)(Bs[cur ^ 1] + sr2 * LDK + sk2) = b_nx;
        }
        __syncthreads();              // one barrier/iter
        cur ^= 1;
    }

    // epilogue: wave owns rows [wr, wr+32), cols [c0+wc, c0+wc+16)
    #pragma unroll
    for (int i = 0; i < 2; i++) {
        int col = c0 + wc + frow;
        int row0 = r0 + wr + i * 16 + quad * 4;
        if (col < DH) {
            #pragma unroll
            for (int r = 0; r < 4; r++)
                Qb[(size_t)(row0 + r) * DH + col] = __float2bfloat16(acc[i][r] * SCALE);
        } else if (col < 2 * DH) {
            #pragma unroll
            for (int r = 0; r < 4; r++)
                Kb[(size_t)(row0 + r) * DH + col - DH] = __float2bfloat16(acc[i][r]);
        } else {
            union { __hip_bfloat16 h[4]; uint2 u; } p;
            #pragma unroll
            for (int r = 0; r < 4; r++) p.h[r] = __float2bfloat16(acc[i][r]);
            *(uint2*)(Vtb + (size_t)(col - 2 * DH) * NTOK + row0) = p.u;
        }
    }
}

// ---------------- fused head kernel (attention + out-proj + norm) ----------
// Unchanged from R8 (single-variable round). Linear-layout residual/norm
// via XOR-swizzled f32 LDS bridge; 4 barriers/head; max-subtraction kept
// (R4: mean drift -> |s|>88 by head 7). OOB band-edge fragment reads land
// in adjacent ws buffers: finite bf16, multiplied by p=0.
__global__ __launch_bounds__(512, 2) void attn_head(const __hip_bfloat16* __restrict__ Qb,
                                                    const __hip_bfloat16* __restrict__ Kb,
                                                    const __hip_bfloat16* __restrict__ Vtb,
                                                    __hip_bfloat16* __restrict__ ebf,
                                                    const __hip_bfloat16* __restrict__ Wvu,
                                                    float* __restrict__ e,
                                                    float* __restrict__ out_final) {
    const int tile = ((blockIdx.x & 7) << 5) | (blockIdx.x >> 3);
    const int q0 = tile * QT;
    const int tid = threadIdx.x;
    const int wave = tid >> 6, lane = tid & 63;       // wave in [0,8)
    const int fr = lane & 15, kg = (lane >> 4) * 8;
    const int quad = lane >> 4;
    const bool last = (out_final != nullptr);

    __shared__ alignas(16) __hip_bfloat16 Us[QT][DH + 8];      // u rows (attn out)
    __shared__ alignas(16) __hip_bfloat16 Pb[QT][NCH * 16 + 8];
    __shared__ alignas(16) float Dls[QT * DEMB];               // delta bridge (swizzled)
    __shared__ float statsA[QT][8];
    __shared__ float statsB[QT][8];

    // ---- e prefetch in LINEAR mapping: thread owns row=tid>>5,
    // cols {j*128 + (tid&31)*4 .. +3}. Written by the SAME tile last launch.
    const int lrow = tid >> 5, l32 = tid & 31;
    floatx4 ev4[8];
    {
        const float* erow = e + (size_t)(q0 + lrow) * DEMB + l32 * 4;
        #pragma unroll
        for (int j = 0; j < 8; j++)
            ev4[j] = *(const floatx4*)(erow + j * 128);
    }

    // ---- Q fragments straight from L2 (pre-scaled) ------------------------
    short8 af[4];
    #pragma unroll
    for (int kc = 0; kc < 4; kc++)
        af[kc] = *(const short8*)(Qb + (size_t)(q0 + fr) * DH + kc * 32 + kg);

    const int kstart = max(q0 - CWIN, 0);
    const int kend   = min(q0 + QT - 1 + CWIN + 1, NTOK);
    const int nch = (wave < 2) ? 5 : 4;   // chunks ch = wave + 8t, ch < 34

    // ---- scores: preload K fragments, then MFMA ---------------------------
    short8 kf[5][4];
    #pragma unroll
    for (int t = 0; t < 5; t++) {
        if (t >= nch) break;
        const __hip_bfloat16* krow = Kb + (size_t)(kstart + (wave + 8 * t) * 16 + fr) * DH;
        #pragma unroll
        for (int kc = 0; kc < 4; kc++)
            kf[t][kc] = *(const short8*)(krow + kc * 32 + kg);
    }
    floatx4 sreg[5];
    #pragma unroll
    for (int t = 0; t < 5; t++) {
        if (t >= nch) break;
        floatx4 s = {};
        #pragma unroll
        for (int kc = 0; kc < 4; kc++)
            s = __builtin_amdgcn_mfma_f32_16x16x32_bf16(af[kc], kf[t][kc], s, 0, 0, 0);
        sreg[t] = s;
    }

    // ---- band mask + per-row max ------------------------------------------
    float pmax[4] = {-1e30f, -1e30f, -1e30f, -1e30f};
    #pragma unroll
    for (int t = 0; t < 5; t++) {
        if (t >= nch) break;
        int tcol = kstart + (wave + 8 * t) * 16 + fr;
        #pragma unroll
        for (int r = 0; r < 4; r++) {
            int qg = q0 + quad * 4 + r;
            bool ok = (tcol < kend) && (tcol >= qg - CWIN) && (tcol < qg + CWIN);
            float v = ok ? sreg[t][r] : -1e30f;
            sreg[t][r] = v;
            pmax[r] = fmaxf(pmax[r], v);
        }
    }
    #pragma unroll
    for (int mm = 1; mm <= 8; mm <<= 1)
        #pragma unroll
        for (int r = 0; r < 4; r++) pmax[r] = fmaxf(pmax[r], __shfl_xor(pmax[r], mm, 64));
    if (fr == 0)
        #pragma unroll
        for (int r = 0; r < 4; r++) statsA[quad * 4 + r][wave] = pmax[r];
    __syncthreads();                                   // bar1: row maxes

    float M[4];
    #pragma unroll
    for (int r = 0; r < 4; r++) {
        int row = quad * 4 + r;
        float m = statsA[row][0];
        #pragma unroll
        for (int w = 1; w < 8; w++) m = fmaxf(m, statsA[row][w]);
        M[r] = m;
    }

    // ---- exp(s - M) -> Pb (A-layout), row sums ----------------------------
    float psum[4] = {};
    #pragma unroll
    for (int t = 0; t < 5; t++) {
        if (t >= nch) break;
        int colb = (wave + 8 * t) * 16 + fr;
        #pragma unroll
        for (int r = 0; r < 4; r++) {
            float p = __expf(sreg[t][r] - M[r]);
            psum[r] += p;
            Pb[quad * 4 + r][colb] = __float2bfloat16(p);
        }
    }
    #pragma unroll
    for (int mm = 1; mm <= 8; mm <<= 1)
        #pragma unroll
        for (int r = 0; r < 4; r++) psum[r] += __shfl_xor(psum[r], mm, 64);
    if (fr == 0)
        #pragma unroll
        for (int r = 0; r < 4; r++) statsB[quad * 4 + r][wave] = psum[r];
    __syncthreads();                                   // bar2: Pb + sums

    float linv[4];
    #pragma unroll
    for (int r = 0; r < 4; r++) {
        int row = quad * 4 + r;
        float s = statsB[row][0];
        #pragma unroll
        for (int w = 1; w < 8; w++) s += statsB[row][w];
        linv[r] = 1.0f / s;
    }

    // ---- PV: wave owns dims [16w,16w+16); 8-deep Vt fragment ring ---------
    {
        const __hip_bfloat16* vbase = Vtb + (size_t)(wave * 16 + fr) * NTOK + kstart + kg;
        short8 vf[8];
        #pragma unroll
        for (int i = 0; i < 8; i++) vf[i] = *(const short8*)(vbase + i * 32);
        floatx4 Of = {};
        #pragma unroll
        for (int kc = 0; kc < NCH / 2; kc++) {
            short8 pf = *(const short8*)&Pb[fr][kc * 32 + kg];
            short8 v = vf[kc & 7];
            if (kc + 8 < NCH / 2) vf[kc & 7] = *(const short8*)(vbase + (kc + 8) * 32);
            Of = __builtin_amdgcn_mfma_f32_16x16x32_bf16(pf, v, Of, 0, 0, 0);
        }
        int col = wave * 16 + fr;
        #pragma unroll
        for (int r = 0; r < 4; r++)
            Us[quad * 4 + r][col] = __float2bfloat16(Of[r] * linv[r]);
    }
    __syncthreads();                                   // bar3: u rows ready
    short8 af2[4];
    #pragma unroll
    for (int kc = 0; kc < 4; kc++) af2[kc] = *(const short8*)&Us[fr][kc * 32 + kg];

    // ---- out-proj: wave owns cols [128w,128w+128); 3-deep Wvu ring --------
    floatx4 accd[8] = {};
    {
        short8 wf[3][4];
        #pragma unroll
        for (int g = 0; g < 2; g++) {
            const __hip_bfloat16* wrow = Wvu + ((size_t)(wave * 128 + g * 16 + fr) << 7);
            #pragma unroll
            for (int kc = 0; kc < 4; kc++) wf[g][kc] = *(const short8*)(wrow + kc * 32 + kg);
        }
        #pragma unroll
        for (int n0 = 0; n0 < 8; n0++) {
            int cur = n0 % 3;
            if (n0 + 2 < 8) {
                int nx = (n0 + 2) % 3;
                const __hip_bfloat16* wrow = Wvu + ((size_t)(wave * 128 + (n0 + 2) * 16 + fr) << 7);
                #pragma unroll
                for (int kc = 0; kc < 4; kc++) wf[nx][kc] = *(const short8*)(wrow + kc * 32 + kg);
            }
            #pragma unroll
            for (int kc = 0; kc < 4; kc++)
                accd[n0] = __builtin_amdgcn_mfma_f32_16x16x32_bf16(af2[kc], wf[cur][kc],
                                                                  accd[n0], 0, 0, 0);
        }
    }

    // ---- delta -> LDS bridge (MFMA layout writer, XOR-swizzled 16B chunks)
    #pragma unroll
    for (int n0 = 0; n0 < 8; n0++) {
        int c_w = wave * 32 + n0 * 4 + (fr >> 2);          // 16B chunk idx in row
        int pc  = c_w ^ ((c_w >> 3) & 7);                  // swizzle (involution)
        #pragma unroll
        for (int r = 0; r < 4; r++)
            Dls[((quad * 4 + r) << 10) + (pc << 2) + (fr & 3)] = accd[n0][r];
    }
    __syncthreads();                                   // bar4: delta ready

    // ---- residual + double-norm in LINEAR mapping -------------------------
    floatx4 dv4[8];
    float s1 = 0.0f, s2 = 0.0f;
    #pragma unroll
    for (int j = 0; j < 8; j++) {
        int c_r = j * 32 + l32;
        int pc  = c_r ^ ((c_r >> 3) & 7);
        floatx4 d = *(const floatx4*)&Dls[(lrow << 10) + (pc << 2)];
        dv4[j] = d;
        #pragma unroll
        for (int k = 0; k < 4; k++) {
            float od = ev4[j][k] + d[k];
            s1 += od; s2 += od * od;
        }
    }
    #pragma unroll
    for (int mm = 1; mm <= 16; mm <<= 1) {             // 32-lane row reduction
        s1 += __shfl_xor(s1, mm, 64);
        s2 += __shfl_xor(s2, mm, 64);
    }
    float m0 = s1 * (1.0f / DEMB);
    float iv = 1.0f / m0;
    float m  = m0 * iv;                                // mean(out/m0) ~ 1
    float st = s1 * iv;
    float var = (s2 * iv * iv - st * st * (1.0f / DEMB)) * (1.0f / (DEMB - 1));
    float isd = rsqrtf(var);

    // ---- final residual+norm; vectorized stores ---------------------------
    {
        float* eout = e + (size_t)(q0 + lrow) * DEMB + l32 * 4;
        __hip_bfloat16* ebout = ebf + (size_t)(q0 + lrow) * DEMB + l32 * 4;
        float* fout = last ? (out_final + (size_t)(q0 + lrow) * DEMB + l32 * 4) : nullptr;
        #pragma unroll
        for (int j = 0; j < 8; j++) {
            floatx4 res;
            #pragma unroll
            for (int k = 0; k < 4; k++) {
                float evv = ev4[j][k];
                float t = (evv + dv4[j][k]) * iv;
                res[k] = evv + (t - m) * isd + m;
            }
            if (last) {
                floatx4 ro = {res[0] * 0.125f, res[1] * 0.125f, res[2] * 0.125f, res[3] * 0.125f};
                *(floatx4*)(fout + j * 128) = ro;
            } else {
                *(floatx4*)(eout + j * 128) = res;
                union { __hip_bfloat16 h[4]; uint2 u; } p;
                #pragma unroll
                for (int k = 0; k < 4; k++) p.h[k] = __float2bfloat16(res[k]);
                *(uint2*)(ebout + j * 128) = p.u;
            }
        }
    }
}

extern "C" void kernel_launch(void* const* d_in, const int* in_sizes, int n_in,
                              void* d_out, int out_size, void* d_ws, size_t ws_size,
                              hipStream_t stream) {
    const float* x   = (const float*)d_in[0];
    const float* Wq  = (const float*)d_in[1];
    const float* Wk  = (const float*)d_in[2];
    const float* Wvd = (const float*)d_in[3];
    const float* Wvu = (const float*)d_in[4];

    char* ws = (char*)d_ws;
    float* e = (float*)ws;                                              // 16 MB
    __hip_bfloat16* ebf   = (__hip_bfloat16*)(ws + (16u << 20));        //  8 MB bf16 mirror of e
    __hip_bfloat16* Qb[2] = {(__hip_bfloat16*)(ws + (24u << 20)),
                             (__hip_bfloat16*)(ws + (27u << 20))};      //  1 MB each
    __hip_bfloat16* Kb[2] = {(__hip_bfloat16*)(ws + (25u << 20)),
                             (__hip_bfloat16*)(ws + (28u << 20))};
    __hip_bfloat16* Vt[2] = {(__hip_bfloat16*)(ws + (26u << 20)),
                             (__hip_bfloat16*)(ws + (29u << 20))};
    __hip_bfloat16* wqkvb = (__hip_bfloat16*)(ws + (30u << 20));        //  6 MB
    __hip_bfloat16* wvub  = (__hip_bfloat16*)(ws + (36u << 20));        //  2 MB  -> 38 MB

    pack_wqkv<<<NH * QKVW * DEMB / 8 / 256, 256, 0, stream>>>(Wq, Wk, Wvd, wqkvb);
    pack_wvu<<<NH * DEMB * DH / 8 / 256, 256, 0, stream>>>(Wvu, wvub);
    init_e<<<NTOK * DEMB / 4 / 256, 256, 0, stream>>>((const float4*)x, (float4*)e, ebf);

    // head-0 QKV from the x mirror
    qkv_gemm_mfma<<<dim3(QKVW / 32, NTOK / 64), 256, 0, stream>>>(
        ebf, wqkvb, Qb[0], Kb[0], Vt[0]);

    for (int h = 0; h < NH; h++) {
        int cur = h & 1, nxt = 1 - cur;
        attn_head<<<NTOK / QT, 512, 0, stream>>>(
            Qb[cur], Kb[cur], Vt[cur],
            ebf, wvub + (size_t)h * DEMB * DH, e,
            (h == NH - 1) ? (float*)d_out : nullptr);
        if (h + 1 < NH)   // de-fused next-head QKV (reads ebf written above)
            qkv_gemm_mfma<<<dim3(QKVW / 32, NTOK / 64), 256, 0, stream>>>(
                ebf, wqkvb + (size_t)(h + 1) * QKVW * DEMB,
                Qb[nxt], Kb[nxt], Vt[nxt]);
    }
}

// Round 13
// 396.424 us; speedup vs baseline: 1.1011x; 1.0507x over previous
//
#include <hip/hip_runtime.h>
#include <hip/hip_bf16.h>

#define NTOK 4096
#define DEMB 1024
#define NH   8
#define DH   128
#define CWIN 256
#define QKVW 384
#define SCALE 0.08838834764831845f   // 1/sqrt(128)
#define QT 16
#define NCH 34                        // 16-key chunks covering the <=528-wide band

typedef __attribute__((ext_vector_type(8))) short short8;
typedef __attribute__((ext_vector_type(4))) short short4v;
typedef __attribute__((ext_vector_type(4))) float floatx4;

__device__ __forceinline__ short8 pack8(float4 a, float4 b) {
    union { __hip_bfloat16 h[8]; short8 v; } o;
    o.h[0] = __float2bfloat16(a.x); o.h[1] = __float2bfloat16(a.y);
    o.h[2] = __float2bfloat16(a.z); o.h[3] = __float2bfloat16(a.w);
    o.h[4] = __float2bfloat16(b.x); o.h[5] = __float2bfloat16(b.y);
    o.h[6] = __float2bfloat16(b.z); o.h[7] = __float2bfloat16(b.w);
    return o.v;
}

// ---------------- weight prep (once per call) ----------------
__global__ void pack_wqkv(const float* __restrict__ Wq, const float* __restrict__ Wk,
                          const float* __restrict__ Wvd, __hip_bfloat16* __restrict__ dst) {
    size_t base = ((size_t)blockIdx.x * 256 + threadIdx.x) * 8;
    int k = (int)(base & 1023);
    int rh = (int)(base >> 10);
    int h = rh / QKVW;
    int row = rh - h * QKVW;
    const float* srcs[3] = {Wq, Wk, Wvd};
    const float* s = srcs[row >> 7] + (((size_t)h * DH + (row & 127)) << 10) + k;
    *(short8*)(dst + base) = pack8(*(const float4*)s, *(const float4*)(s + 4));
}

__global__ void pack_wvu(const float* __restrict__ Wvu, __hip_bfloat16* __restrict__ dst) {
    size_t base = ((size_t)blockIdx.x * 256 + threadIdx.x) * 8;
    *(short8*)(dst + base) = pack8(*(const float4*)(Wvu + base), *(const float4*)(Wvu + base + 4));
}

// ---------------- stage 0: e = x (+ bf16 mirror) ---------------------------
__global__ void init_e(const float4* __restrict__ x, float4* __restrict__ e,
                       __hip_bfloat16* __restrict__ ebf) {
    int i = blockIdx.x * 256 + threadIdx.x;
    float4 v = x[i];
    e[i] = v;
    union { __hip_bfloat16 h[4]; uint2 u; } p;
    p.h[0] = __float2bfloat16(v.x); p.h[1] = __float2bfloat16(v.y);
    p.h[2] = __float2bfloat16(v.z); p.h[3] = __float2bfloat16(v.w);
    *(uint2*)(ebf + (size_t)i * 4) = p.u;
}

// ---------------- per-head qkv GEMM: emits Q (scaled), K, V^T --------------
// R11 confirmed cross-block TLP (-20us total). This round adds XCD
// producer/consumer alignment: attn tiles use slab map XCD = row>>9; qkv's
// default x-major round-robin scattered row-panels across XCDs, making
// qkv's ebf reads AND attn's K/Vt reads ~7/8 remote (L3 ~450cyc vs L2
// ~200cyc). Bijective remap: linear=y*12+x; xcd=linear&7; idx=linear>>3;
// y'=xcd*8+(idx&7); x'=idx>>3 -> row-panel y' lands on XCD y'>>3, matching
// attn's slab. Producer->consumer now XCD-local both directions.
__global__ __launch_bounds__(256) void qkv_gemm_mfma(const __hip_bfloat16* __restrict__ A,
                                                     const __hip_bfloat16* __restrict__ B,
                                                     __hip_bfloat16* __restrict__ Qb,
                                                     __hip_bfloat16* __restrict__ Kb,
                                                     __hip_bfloat16* __restrict__ Vtb) {
    constexpr int K = DEMB;
    constexpr int LDK = 40;
    // XCD slab alignment remap (bijective on 12x64):
    const int linear = blockIdx.y * 12 + blockIdx.x;
    const int xcd = linear & 7, idx = linear >> 3;
    const int by = xcd * 8 + (idx & 7);    // row-panel -> XCD by>>3 == row>>9
    const int bx = idx >> 3;               // 0..11
    const int c0 = bx * 32, r0 = by * 64;
    const int tid = threadIdx.x;
    const int wave = tid >> 6, lane = tid & 63;
    const int wr = (wave >> 1) * 32, wc = (wave & 1) * 16;
    const int frow = lane & 15, kgrp = (lane >> 4) * 8;
    const int quad = lane >> 4;
    const int sr = tid >> 2, sk = (tid & 3) * 8;       // A staging: 64 rows x 32
    const int sr2 = tid >> 3, sk2 = (tid & 7) * 4;     // B staging: 32 rows x 32

    __shared__ __hip_bfloat16 As[2][64 * LDK];
    __shared__ __hip_bfloat16 Bs[2][32 * LDK];

    const __hip_bfloat16* arow = A + (size_t)(r0 + sr) * K + sk;
    const __hip_bfloat16* brow = B + (size_t)(c0 + sr2) * K + sk2;

    // prologue: stage k0=0 into buf0
    *(short8*)(As[0] + sr * LDK + sk) = *(const short8*)(arow);
    *(short4v*)(Bs[0] + sr2 * LDK + sk2) = *(const short4v*)(brow);
    __syncthreads();

    floatx4 acc[2] = {};
    int cur = 0;

    for (int k0 = 0; k0 < K; k0 += 32) {
        short8 a_nx; short4v b_nx;
        const bool more = (k0 + 32 < K);
        if (more) {
            a_nx = *(const short8*)(arow + k0 + 32);
            b_nx = *(const short4v*)(brow + k0 + 32);
        }

        short8 a0 = *(const short8*)(As[cur] + (wr + frow) * LDK + kgrp);
        short8 a1 = *(const short8*)(As[cur] + (wr + 16 + frow) * LDK + kgrp);
        short8 b0 = *(const short8*)(Bs[cur] + (wc + frow) * LDK + kgrp);
        acc[0] = __builtin_amdgcn_mfma_f32_16x16x32_bf16(a0, b0, acc[0], 0, 0, 0);
        acc[1] = __builtin_amdgcn_mfma_f32_16x16x32_bf16(a1, b0, acc[1], 0, 0, 0);

        if (more) {
            *(short8*)(As[cur ^ 1] + sr * LDK + sk) = a_nx;
            *(short4v*)(Bs[cur ^ 1] + sr2 * LDK + sk2) = b_nx;
        }
        __syncthreads();              // one barrier/iter
        cur ^= 1;
    }

    // epilogue: wave owns rows [wr, wr+32), cols [c0+wc, c0+wc+16)
    #pragma unroll
    for (int i = 0; i < 2; i++) {
        int col = c0 + wc + frow;
        int row0 = r0 + wr + i * 16 + quad * 4;
        if (col < DH) {
            #pragma unroll
            for (int r = 0; r < 4; r++)
                Qb[(size_t)(row0 + r) * DH + col] = __float2bfloat16(acc[i][r] * SCALE);
        } else if (col < 2 * DH) {
            #pragma unroll
            for (int r = 0; r < 4; r++)
                Kb[(size_t)(row0 + r) * DH + col - DH] = __float2bfloat16(acc[i][r]);
        } else {
            union { __hip_bfloat16 h[4]; uint2 u; } p;
            #pragma unroll
            for (int r = 0; r < 4; r++) p.h[r] = __float2bfloat16(acc[i][r]);
            *(uint2*)(Vtb + (size_t)(col - 2 * DH) * NTOK + row0) = p.u;
        }
    }
}

// ---------------- fused head kernel (attention + out-proj + norm) ----------
// Unchanged from R11 winner (single-variable round). Linear-layout
// residual/norm via XOR-swizzled f32 LDS bridge; 4 barriers/head;
// max-subtraction kept (R4: mean drift -> |s|>88 by head 7). OOB band-edge
// fragment reads land in adjacent ws buffers: finite bf16, x p=0.
__global__ __launch_bounds__(512, 2) void attn_head(const __hip_bfloat16* __restrict__ Qb,
                                                    const __hip_bfloat16* __restrict__ Kb,
                                                    const __hip_bfloat16* __restrict__ Vtb,
                                                    __hip_bfloat16* __restrict__ ebf,
                                                    const __hip_bfloat16* __restrict__ Wvu,
                                                    float* __restrict__ e,
                                                    float* __restrict__ out_final) {
    const int tile = ((blockIdx.x & 7) << 5) | (blockIdx.x >> 3);
    const int q0 = tile * QT;
    const int tid = threadIdx.x;
    const int wave = tid >> 6, lane = tid & 63;       // wave in [0,8)
    const int fr = lane & 15, kg = (lane >> 4) * 8;
    const int quad = lane >> 4;
    const bool last = (out_final != nullptr);

    __shared__ alignas(16) __hip_bfloat16 Us[QT][DH + 8];      // u rows (attn out)
    __shared__ alignas(16) __hip_bfloat16 Pb[QT][NCH * 16 + 8];
    __shared__ alignas(16) float Dls[QT * DEMB];               // delta bridge (swizzled)
    __shared__ float statsA[QT][8];
    __shared__ float statsB[QT][8];

    // ---- e prefetch in LINEAR mapping: thread owns row=tid>>5,
    // cols {j*128 + (tid&31)*4 .. +3}. Written by the SAME tile last launch.
    const int lrow = tid >> 5, l32 = tid & 31;
    floatx4 ev4[8];
    {
        const float* erow = e + (size_t)(q0 + lrow) * DEMB + l32 * 4;
        #pragma unroll
        for (int j = 0; j < 8; j++)
            ev4[j] = *(const floatx4*)(erow + j * 128);
    }

    // ---- Q fragments straight from L2 (pre-scaled) ------------------------
    short8 af[4];
    #pragma unroll
    for (int kc = 0; kc < 4; kc++)
        af[kc] = *(const short8*)(Qb + (size_t)(q0 + fr) * DH + kc * 32 + kg);

    const int kstart = max(q0 - CWIN, 0);
    const int kend   = min(q0 + QT - 1 + CWIN + 1, NTOK);
    const int nch = (wave < 2) ? 5 : 4;   // chunks ch = wave + 8t, ch < 34

    // ---- scores: preload K fragments, then MFMA ---------------------------
    short8 kf[5][4];
    #pragma unroll
    for (int t = 0; t < 5; t++) {
        if (t >= nch) break;
        const __hip_bfloat16* krow = Kb + (size_t)(kstart + (wave + 8 * t) * 16 + fr) * DH;
        #pragma unroll
        for (int kc = 0; kc < 4; kc++)
            kf[t][kc] = *(const short8*)(krow + kc * 32 + kg);
    }
    floatx4 sreg[5];
    #pragma unroll
    for (int t = 0; t < 5; t++) {
        if (t >= nch) break;
        floatx4 s = {};
        #pragma unroll
        for (int kc = 0; kc < 4; kc++)
            s = __builtin_amdgcn_mfma_f32_16x16x32_bf16(af[kc], kf[t][kc], s, 0, 0, 0);
        sreg[t] = s;
    }

    // ---- band mask + per-row max ------------------------------------------
    float pmax[4] = {-1e30f, -1e30f, -1e30f, -1e30f};
    #pragma unroll
    for (int t = 0; t < 5; t++) {
        if (t >= nch) break;
        int tcol = kstart + (wave + 8 * t) * 16 + fr;
        #pragma unroll
        for (int r = 0; r < 4; r++) {
            int qg = q0 + quad * 4 + r;
            bool ok = (tcol < kend) && (tcol >= qg - CWIN) && (tcol < qg + CWIN);
            float v = ok ? sreg[t][r] : -1e30f;
            sreg[t][r] = v;
            pmax[r] = fmaxf(pmax[r], v);
        }
    }
    #pragma unroll
    for (int mm = 1; mm <= 8; mm <<= 1)
        #pragma unroll
        for (int r = 0; r < 4; r++) pmax[r] = fmaxf(pmax[r], __shfl_xor(pmax[r], mm, 64));
    if (fr == 0)
        #pragma unroll
        for (int r = 0; r < 4; r++) statsA[quad * 4 + r][wave] = pmax[r];
    __syncthreads();                                   // bar1: row maxes

    float M[4];
    #pragma unroll
    for (int r = 0; r < 4; r++) {
        int row = quad * 4 + r;
        float m = statsA[row][0];
        #pragma unroll
        for (int w = 1; w < 8; w++) m = fmaxf(m, statsA[row][w]);
        M[r] = m;
    }

    // ---- exp(s - M) -> Pb (A-layout), row sums ----------------------------
    float psum[4] = {};
    #pragma unroll
    for (int t = 0; t < 5; t++) {
        if (t >= nch) break;
        int colb = (wave + 8 * t) * 16 + fr;
        #pragma unroll
        for (int r = 0; r < 4; r++) {
            float p = __expf(sreg[t][r] - M[r]);
            psum[r] += p;
            Pb[quad * 4 + r][colb] = __float2bfloat16(p);
        }
    }
    #pragma unroll
    for (int mm = 1; mm <= 8; mm <<= 1)
        #pragma unroll
        for (int r = 0; r < 4; r++) psum[r] += __shfl_xor(psum[r], mm, 64);
    if (fr == 0)
        #pragma unroll
        for (int r = 0; r < 4; r++) statsB[quad * 4 + r][wave] = psum[r];
    __syncthreads();                                   // bar2: Pb + sums

    float linv[4];
    #pragma unroll
    for (int r = 0; r < 4; r++) {
        int row = quad * 4 + r;
        float s = statsB[row][0];
        #pragma unroll
        for (int w = 1; w < 8; w++) s += statsB[row][w];
        linv[r] = 1.0f / s;
    }

    // ---- PV: wave owns dims [16w,16w+16); 8-deep Vt fragment ring ---------
    {
        const __hip_bfloat16* vbase = Vtb + (size_t)(wave * 16 + fr) * NTOK + kstart + kg;
        short8 vf[8];
        #pragma unroll
        for (int i = 0; i < 8; i++) vf[i] = *(const short8*)(vbase + i * 32);
        floatx4 Of = {};
        #pragma unroll
        for (int kc = 0; kc < NCH / 2; kc++) {
            short8 pf = *(const short8*)&Pb[fr][kc * 32 + kg];
            short8 v = vf[kc & 7];
            if (kc + 8 < NCH / 2) vf[kc & 7] = *(const short8*)(vbase + (kc + 8) * 32);
            Of = __builtin_amdgcn_mfma_f32_16x16x32_bf16(pf, v, Of, 0, 0, 0);
        }
        int col = wave * 16 + fr;
        #pragma unroll
        for (int r = 0; r < 4; r++)
            Us[quad * 4 + r][col] = __float2bfloat16(Of[r] * linv[r]);
    }
    __syncthreads();                                   // bar3: u rows ready
    short8 af2[4];
    #pragma unroll
    for (int kc = 0; kc < 4; kc++) af2[kc] = *(const short8*)&Us[fr][kc * 32 + kg];

    // ---- out-proj: wave owns cols [128w,128w+128); 3-deep Wvu ring --------
    floatx4 accd[8] = {};
    {
        short8 wf[3][4];
        #pragma unroll
        for (int g = 0; g < 2; g++) {
            const __hip_bfloat16* wrow = Wvu + ((size_t)(wave * 128 + g * 16 + fr) << 7);
            #pragma unroll
            for (int kc = 0; kc < 4; kc++) wf[g][kc] = *(const short8*)(wrow + kc * 32 + kg);
        }
        #pragma unroll
        for (int n0 = 0; n0 < 8; n0++) {
            int cur = n0 % 3;
            if (n0 + 2 < 8) {
                int nx = (n0 + 2) % 3;
                const __hip_bfloat16* wrow = Wvu + ((size_t)(wave * 128 + (n0 + 2) * 16 + fr) << 7);
                #pragma unroll
                for (int kc = 0; kc < 4; kc++) wf[nx][kc] = *(const short8*)(wrow + kc * 32 + kg);
            }
            #pragma unroll
            for (int kc = 0; kc < 4; kc++)
                accd[n0] = __builtin_amdgcn_mfma_f32_16x16x32_bf16(af2[kc], wf[cur][kc],
                                                                  accd[n0], 0, 0, 0);
        }
    }

    // ---- delta -> LDS bridge (MFMA layout writer, XOR-swizzled 16B chunks)
    #pragma unroll
    for (int n0 = 0; n0 < 8; n0++) {
        int c_w = wave * 32 + n0 * 4 + (fr >> 2);          // 16B chunk idx in row
        int pc  = c_w ^ ((c_w >> 3) & 7);                  // swizzle (involution)
        #pragma unroll
        for (int r = 0; r < 4; r++)
            Dls[((quad * 4 + r) << 10) + (pc << 2) + (fr & 3)] = accd[n0][r];
    }
    __syncthreads();                                   // bar4: delta ready

    // ---- residual + double-norm in LINEAR mapping -------------------------
    floatx4 dv4[8];
    float s1 = 0.0f, s2 = 0.0f;
    #pragma unroll
    for (int j = 0; j < 8; j++) {
        int c_r = j * 32 + l32;
        int pc  = c_r ^ ((c_r >> 3) & 7);
        floatx4 d = *(const floatx4*)&Dls[(lrow << 10) + (pc << 2)];
        dv4[j] = d;
        #pragma unroll
        for (int k = 0; k < 4; k++) {
            float od = ev4[j][k] + d[k];
            s1 += od; s2 += od * od;
        }
    }
    #pragma unroll
    for (int mm = 1; mm <= 16; mm <<= 1) {             // 32-lane row reduction
        s1 += __shfl_xor(s1, mm, 64);
        s2 += __shfl_xor(s2, mm, 64);
    }
    float m0 = s1 * (1.0f / DEMB);
    float iv = 1.0f / m0;
    float m  = m0 * iv;                                // mean(out/m0) ~ 1
    float st = s1 * iv;
    float var = (s2 * iv * iv - st * st * (1.0f / DEMB)) * (1.0f / (DEMB - 1));
    float isd = rsqrtf(var);

    // ---- final residual+norm; vectorized stores ---------------------------
    {
        float* eout = e + (size_t)(q0 + lrow) * DEMB + l32 * 4;
        __hip_bfloat16* ebout = ebf + (size_t)(q0 + lrow) * DEMB + l32 * 4;
        float* fout = last ? (out_final + (size_t)(q0 + lrow) * DEMB + l32 * 4) : nullptr;
        #pragma unroll
        for (int j = 0; j < 8; j++) {
            floatx4 res;
            #pragma unroll
            for (int k = 0; k < 4; k++) {
                float evv = ev4[j][k];
                float t = (evv + dv4[j][k]) * iv;
                res[k] = evv + (t - m) * isd + m;
            }
            if (last) {
                floatx4 ro = {res[0] * 0.125f, res[1] * 0.125f, res[2] * 0.125f, res[3] * 0.125f};
                *(floatx4*)(fout + j * 128) = ro;
            } else {
                *(floatx4*)(eout + j * 128) = res;
                union { __hip_bfloat16 h[4]; uint2 u; } p;
                #pragma unroll
                for (int k = 0; k < 4; k++) p.h[k] = __float2bfloat16(res[k]);
                *(uint2*)(ebout + j * 128) = p.u;
            }
        }
    }
}

extern "C" void kernel_launch(void* const* d_in, const int* in_sizes, int n_in,
                              void* d_out, int out_size, void* d_ws, size_t ws_size,
                              hipStream_t stream) {
    const float* x   = (const float*)d_in[0];
    const float* Wq  = (const float*)d_in[1];
    const float* Wk  = (const float*)d_in[2];
    const float* Wvd = (const float*)d_in[3];
    const float* Wvu = (const float*)d_in[4];

    char* ws = (char*)d_ws;
    float* e = (float*)ws;                                              // 16 MB
    __hip_bfloat16* ebf   = (__hip_bfloat16*)(ws + (16u << 20));        //  8 MB bf16 mirror of e
    __hip_bfloat16* Qb[2] = {(__hip_bfloat16*)(ws + (24u << 20)),
                             (__hip_bfloat16*)(ws + (27u << 20))};      //  1 MB each
    __hip_bfloat16* Kb[2] = {(__hip_bfloat16*)(ws + (25u << 20)),
                             (__hip_bfloat16*)(ws + (28u << 20))};
    __hip_bfloat16* Vt[2] = {(__hip_bfloat16*)(ws + (26u << 20)),
                             (__hip_bfloat16*)(ws + (29u << 20))};
    __hip_bfloat16* wqkvb = (__hip_bfloat16*)(ws + (30u << 20));        //  6 MB
    __hip_bfloat16* wvub  = (__hip_bfloat16*)(ws + (36u << 20));        //  2 MB  -> 38 MB

    pack_wqkv<<<NH * QKVW * DEMB / 8 / 256, 256, 0, stream>>>(Wq, Wk, Wvd, wqkvb);
    pack_wvu<<<NH * DEMB * DH / 8 / 256, 256, 0, stream>>>(Wvu, wvub);
    init_e<<<NTOK * DEMB / 4 / 256, 256, 0, stream>>>((const float4*)x, (float4*)e, ebf);

    // head-0 QKV from the x mirror
    qkv_gemm_mfma<<<dim3(QKVW / 32, NTOK / 64), 256, 0, stream>>>(
        ebf, wqkvb, Qb[0], Kb[0], Vt[0]);

    for (int h = 0; h < NH; h++) {
        int cur = h & 1, nxt = 1 - cur;
        attn_head<<<NTOK / QT, 512, 0, stream>>>(
            Qb[cur], Kb[cur], Vt[cur],
            ebf, wvub + (size_t)h * DEMB * DH, e,
            (h == NH - 1) ? (float*)d_out : nullptr);
        if (h + 1 < NH)   // de-fused next-head QKV (reads ebf written above)
            qkv_gemm_mfma<<<dim3(QKVW / 32, NTOK / 64), 256, 0, stream>>>(
                ebf, wqkvb + (size_t)(h + 1) * QKVW * DEMB,
                Qb[nxt], Kb[nxt], Vt[nxt]);
    }
}

// Round 16
// 366.024 us; speedup vs baseline: 1.1926x; 1.0831x over previous
//
#include <hip/hip_runtime.h>
#include <hip/hip_bf16.h>

#define NTOK 4096
#define DEMB 1024
#define NH   8
#define DH   128
#define CWIN 256
#define QKVW 384
#define SCALE 0.08838834764831845f   // 1/sqrt(128)
#define QT 16
#define NCH 34                        // 16-key chunks covering the <=528-wide band

typedef __attribute__((ext_vector_type(8))) short short8;
typedef __attribute__((ext_vector_type(4))) float floatx4;

__device__ __forceinline__ short8 pack8(float4 a, float4 b) {
    union { __hip_bfloat16 h[8]; short8 v; } o;
    o.h[0] = __float2bfloat16(a.x); o.h[1] = __float2bfloat16(a.y);
    o.h[2] = __float2bfloat16(a.z); o.h[3] = __float2bfloat16(a.w);
    o.h[4] = __float2bfloat16(b.x); o.h[5] = __float2bfloat16(b.y);
    o.h[6] = __float2bfloat16(b.z); o.h[7] = __float2bfloat16(b.w);
    return o.v;
}

// ---------------- weight prep (once per call) ----------------
__global__ void pack_wqkv(const float* __restrict__ Wq, const float* __restrict__ Wk,
                          const float* __restrict__ Wvd, __hip_bfloat16* __restrict__ dst) {
    size_t base = ((size_t)blockIdx.x * 256 + threadIdx.x) * 8;
    int k = (int)(base & 1023);
    int rh = (int)(base >> 10);
    int h = rh / QKVW;
    int row = rh - h * QKVW;
    const float* srcs[3] = {Wq, Wk, Wvd};
    const float* s = srcs[row >> 7] + (((size_t)h * DH + (row & 127)) << 10) + k;
    *(short8*)(dst + base) = pack8(*(const float4*)s, *(const float4*)(s + 4));
}

__global__ void pack_wvu(const float* __restrict__ Wvu, __hip_bfloat16* __restrict__ dst) {
    size_t base = ((size_t)blockIdx.x * 256 + threadIdx.x) * 8;
    *(short8*)(dst + base) = pack8(*(const float4*)(Wvu + base), *(const float4*)(Wvu + base + 4));
}

// ---------------- stage 0: e = x (+ bf16 mirror) ---------------------------
__global__ void init_e(const float4* __restrict__ x, float4* __restrict__ e,
                       __hip_bfloat16* __restrict__ ebf) {
    int i = blockIdx.x * 256 + threadIdx.x;
    float4 v = x[i];
    e[i] = v;
    union { __hip_bfloat16 h[4]; uint2 u; } p;
    p.h[0] = __float2bfloat16(v.x); p.h[1] = __float2bfloat16(v.y);
    p.h[2] = __float2bfloat16(v.z); p.h[3] = __float2bfloat16(v.w);
    *(uint2*)(ebf + (size_t)i * 4) = p.u;
}

// ---------------- per-head qkv GEMM: emits Q (scaled), K, V^T --------------
// BK=64 (kept from R15 bisection): halves iterations (32->16) and barrier
// drains; per-iter staging = 3 independent loads (MLP 3); 6 ds_read +
// 4 MFMA amortize each barrier 2x. LDS 27.6 KB dbuf (LDK=72 -> stride 36
// words -> 2-way bank aliasing, free per m136). Grid 768 = 3 blocks/CU;
// XCD slab-aligned remap (R13 win): row-panel by -> XCD by>>3 matches
// attn's tile map, so ebf reads and K/Vt consumers stay XCD-local.
__global__ __launch_bounds__(256) void qkv_gemm_mfma(const __hip_bfloat16* __restrict__ A,
                                                     const __hip_bfloat16* __restrict__ B,
                                                     __hip_bfloat16* __restrict__ Qb,
                                                     __hip_bfloat16* __restrict__ Kb,
                                                     __hip_bfloat16* __restrict__ Vtb) {
    constexpr int K = DEMB;
    constexpr int LDK = 72;
    // XCD slab alignment remap (bijective on 12x64):
    const int linear = blockIdx.y * 12 + blockIdx.x;
    const int xcd = linear & 7, idx = linear >> 3;
    const int by = xcd * 8 + (idx & 7);
    const int bx = idx >> 3;
    const int c0 = bx * 32, r0 = by * 64;
    const int tid = threadIdx.x;
    const int wave = tid >> 6, lane = tid & 63;
    const int wr = (wave >> 1) * 32, wc = (wave & 1) * 16;
    const int frow = lane & 15, kgrp = (lane >> 4) * 8;
    const int quad = lane >> 4;
    const int sr = tid >> 2, sk = (tid & 3) * 16;      // A staging: 64 rows x 64 (2 short8/thr)
    const int sr2 = tid >> 3, sk2 = (tid & 7) * 8;     // B staging: 32 rows x 64 (1 short8/thr)

    __shared__ __hip_bfloat16 As[2][64 * LDK];
    __shared__ __hip_bfloat16 Bs[2][32 * LDK];

    const __hip_bfloat16* arow = A + (size_t)(r0 + sr) * K + sk;
    const __hip_bfloat16* brow = B + (size_t)(c0 + sr2) * K + sk2;

    // prologue: stage k0=0 into buf0
    *(short8*)(As[0] + sr * LDK + sk)     = *(const short8*)(arow);
    *(short8*)(As[0] + sr * LDK + sk + 8) = *(const short8*)(arow + 8);
    *(short8*)(Bs[0] + sr2 * LDK + sk2)   = *(const short8*)(brow);
    __syncthreads();

    floatx4 acc[2] = {};
    int cur = 0;

    for (int k0 = 0; k0 < K; k0 += 64) {
        short8 a_nx0, a_nx1, b_nx;
        const bool more = (k0 + 64 < K);
        if (more) {   // issue next staging loads early; latency hides under MFMAs
            a_nx0 = *(const short8*)(arow + k0 + 64);
            a_nx1 = *(const short8*)(arow + k0 + 72);
            b_nx  = *(const short8*)(brow + k0 + 64);
        }

        #pragma unroll
        for (int kk = 0; kk < 64; kk += 32) {
            short8 a0 = *(const short8*)(As[cur] + (wr + frow) * LDK + kk + kgrp);
            short8 a1 = *(const short8*)(As[cur] + (wr + 16 + frow) * LDK + kk + kgrp);
            short8 b0 = *(const short8*)(Bs[cur] + (wc + frow) * LDK + kk + kgrp);
            acc[0] = __builtin_amdgcn_mfma_f32_16x16x32_bf16(a0, b0, acc[0], 0, 0, 0);
            acc[1] = __builtin_amdgcn_mfma_f32_16x16x32_bf16(a1, b0, acc[1], 0, 0, 0);
        }

        if (more) {
            *(short8*)(As[cur ^ 1] + sr * LDK + sk)     = a_nx0;
            *(short8*)(As[cur ^ 1] + sr * LDK + sk + 8) = a_nx1;
            *(short8*)(Bs[cur ^ 1] + sr2 * LDK + sk2)   = b_nx;
        }
        __syncthreads();              // one barrier/iter
        cur ^= 1;
    }

    // epilogue: wave owns rows [wr, wr+32), cols [c0+wc, c0+wc+16)
    #pragma unroll
    for (int i = 0; i < 2; i++) {
        int col = c0 + wc + frow;
        int row0 = r0 + wr + i * 16 + quad * 4;
        if (col < DH) {
            #pragma unroll
            for (int r = 0; r < 4; r++)
                Qb[(size_t)(row0 + r) * DH + col] = __float2bfloat16(acc[i][r] * SCALE);
        } else if (col < 2 * DH) {
            #pragma unroll
            for (int r = 0; r < 4; r++)
                Kb[(size_t)(row0 + r) * DH + col - DH] = __float2bfloat16(acc[i][r]);
        } else {
            union { __hip_bfloat16 h[4]; uint2 u; } p;
            #pragma unroll
            for (int r = 0; r < 4; r++) p.h[r] = __float2bfloat16(acc[i][r]);
            *(uint2*)(Vtb + (size_t)(col - 2 * DH) * NTOK + row0) = p.u;
        }
    }
}

// ---------------- fused head kernel (attention + out-proj + norm) ----------
// REVERTED to the R13-passing version verbatim (bisection: R15's
// constant-trip dummy-read variant failed replay-idempotency; the OOB
// dummy reads are the suspect). Linear-layout residual/norm via
// XOR-swizzled f32 LDS bridge; 4 barriers/head; max-subtraction kept
// (R4: mean drift -> |s|>88 by head 7). OOB band-edge fragment reads land
// in adjacent ws buffers: finite bf16, x p=0.
__global__ __launch_bounds__(512, 2) void attn_head(const __hip_bfloat16* __restrict__ Qb,
                                                    const __hip_bfloat16* __restrict__ Kb,
                                                    const __hip_bfloat16* __restrict__ Vtb,
                                                    __hip_bfloat16* __restrict__ ebf,
                                                    const __hip_bfloat16* __restrict__ Wvu,
                                                    float* __restrict__ e,
                                                    float* __restrict__ out_final) {
    const int tile = ((blockIdx.x & 7) << 5) | (blockIdx.x >> 3);
    const int q0 = tile * QT;
    const int tid = threadIdx.x;
    const int wave = tid >> 6, lane = tid & 63;       // wave in [0,8)
    const int fr = lane & 15, kg = (lane >> 4) * 8;
    const int quad = lane >> 4;
    const bool last = (out_final != nullptr);

    __shared__ alignas(16) __hip_bfloat16 Us[QT][DH + 8];      // u rows (attn out)
    __shared__ alignas(16) __hip_bfloat16 Pb[QT][NCH * 16 + 8];
    __shared__ alignas(16) float Dls[QT * DEMB];               // delta bridge (swizzled)
    __shared__ float statsA[QT][8];
    __shared__ float statsB[QT][8];

    // ---- e prefetch in LINEAR mapping: thread owns row=tid>>5,
    // cols {j*128 + (tid&31)*4 .. +3}. Written by the SAME tile last launch.
    const int lrow = tid >> 5, l32 = tid & 31;
    floatx4 ev4[8];
    {
        const float* erow = e + (size_t)(q0 + lrow) * DEMB + l32 * 4;
        #pragma unroll
        for (int j = 0; j < 8; j++)
            ev4[j] = *(const floatx4*)(erow + j * 128);
    }

    // ---- Q fragments straight from L2 (pre-scaled) ------------------------
    short8 af[4];
    #pragma unroll
    for (int kc = 0; kc < 4; kc++)
        af[kc] = *(const short8*)(Qb + (size_t)(q0 + fr) * DH + kc * 32 + kg);

    const int kstart = max(q0 - CWIN, 0);
    const int kend   = min(q0 + QT - 1 + CWIN + 1, NTOK);
    const int nch = (wave < 2) ? 5 : 4;   // chunks ch = wave + 8t, ch < 34

    // ---- scores: preload K fragments, then MFMA ---------------------------
    short8 kf[5][4];
    #pragma unroll
    for (int t = 0; t < 5; t++) {
        if (t >= nch) break;
        const __hip_bfloat16* krow = Kb + (size_t)(kstart + (wave + 8 * t) * 16 + fr) * DH;
        #pragma unroll
        for (int kc = 0; kc < 4; kc++)
            kf[t][kc] = *(const short8*)(krow + kc * 32 + kg);
    }
    floatx4 sreg[5];
    #pragma unroll
    for (int t = 0; t < 5; t++) {
        if (t >= nch) break;
        floatx4 s = {};
        #pragma unroll
        for (int kc = 0; kc < 4; kc++)
            s = __builtin_amdgcn_mfma_f32_16x16x32_bf16(af[kc], kf[t][kc], s, 0, 0, 0);
        sreg[t] = s;
    }

    // ---- band mask + per-row max ------------------------------------------
    float pmax[4] = {-1e30f, -1e30f, -1e30f, -1e30f};
    #pragma unroll
    for (int t = 0; t < 5; t++) {
        if (t >= nch) break;
        int tcol = kstart + (wave + 8 * t) * 16 + fr;
        #pragma unroll
        for (int r = 0; r < 4; r++) {
            int qg = q0 + quad * 4 + r;
            bool ok = (tcol < kend) && (tcol >= qg - CWIN) && (tcol < qg + CWIN);
            float v = ok ? sreg[t][r] : -1e30f;
            sreg[t][r] = v;
            pmax[r] = fmaxf(pmax[r], v);
        }
    }
    #pragma unroll
    for (int mm = 1; mm <= 8; mm <<= 1)
        #pragma unroll
        for (int r = 0; r < 4; r++) pmax[r] = fmaxf(pmax[r], __shfl_xor(pmax[r], mm, 64));
    if (fr == 0)
        #pragma unroll
        for (int r = 0; r < 4; r++) statsA[quad * 4 + r][wave] = pmax[r];
    __syncthreads();                                   // bar1: row maxes

    float M[4];
    #pragma unroll
    for (int r = 0; r < 4; r++) {
        int row = quad * 4 + r;
        float m = statsA[row][0];
        #pragma unroll
        for (int w = 1; w < 8; w++) m = fmaxf(m, statsA[row][w]);
        M[r] = m;
    }

    // ---- exp(s - M) -> Pb (A-layout), row sums ----------------------------
    float psum[4] = {};
    #pragma unroll
    for (int t = 0; t < 5; t++) {
        if (t >= nch) break;
        int colb = (wave + 8 * t) * 16 + fr;
        #pragma unroll
        for (int r = 0; r < 4; r++) {
            float p = __expf(sreg[t][r] - M[r]);
            psum[r] += p;
            Pb[quad * 4 + r][colb] = __float2bfloat16(p);
        }
    }
    #pragma unroll
    for (int mm = 1; mm <= 8; mm <<= 1)
        #pragma unroll
        for (int r = 0; r < 4; r++) psum[r] += __shfl_xor(psum[r], mm, 64);
    if (fr == 0)
        #pragma unroll
        for (int r = 0; r < 4; r++) statsB[quad * 4 + r][wave] = psum[r];
    __syncthreads();                                   // bar2: Pb + sums

    float linv[4];
    #pragma unroll
    for (int r = 0; r < 4; r++) {
        int row = quad * 4 + r;
        float s = statsB[row][0];
        #pragma unroll
        for (int w = 1; w < 8; w++) s += statsB[row][w];
        linv[r] = 1.0f / s;
    }

    // ---- PV: wave owns dims [16w,16w+16); 8-deep Vt fragment ring ---------
    {
        const __hip_bfloat16* vbase = Vtb + (size_t)(wave * 16 + fr) * NTOK + kstart + kg;
        short8 vf[8];
        #pragma unroll
        for (int i = 0; i < 8; i++) vf[i] = *(const short8*)(vbase + i * 32);
        floatx4 Of = {};
        #pragma unroll
        for (int kc = 0; kc < NCH / 2; kc++) {
            short8 pf = *(const short8*)&Pb[fr][kc * 32 + kg];
            short8 v = vf[kc & 7];
            if (kc + 8 < NCH / 2) vf[kc & 7] = *(const short8*)(vbase + (kc + 8) * 32);
            Of = __builtin_amdgcn_mfma_f32_16x16x32_bf16(pf, v, Of, 0, 0, 0);
        }
        int col = wave * 16 + fr;
        #pragma unroll
        for (int r = 0; r < 4; r++)
            Us[quad * 4 + r][col] = __float2bfloat16(Of[r] * linv[r]);
    }
    __syncthreads();                                   // bar3: u rows ready
    short8 af2[4];
    #pragma unroll
    for (int kc = 0; kc < 4; kc++) af2[kc] = *(const short8*)&Us[fr][kc * 32 + kg];

    // ---- out-proj: wave owns cols [128w,128w+128); 3-deep Wvu ring --------
    floatx4 accd[8] = {};
    {
        short8 wf[3][4];
        #pragma unroll
        for (int g = 0; g < 2; g++) {
            const __hip_bfloat16* wrow = Wvu + ((size_t)(wave * 128 + g * 16 + fr) << 7);
            #pragma unroll
            for (int kc = 0; kc < 4; kc++) wf[g][kc] = *(const short8*)(wrow + kc * 32 + kg);
        }
        #pragma unroll
        for (int n0 = 0; n0 < 8; n0++) {
            int cur = n0 % 3;
            if (n0 + 2 < 8) {
                int nx = (n0 + 2) % 3;
                const __hip_bfloat16* wrow = Wvu + ((size_t)(wave * 128 + (n0 + 2) * 16 + fr) << 7);
                #pragma unroll
                for (int kc = 0; kc < 4; kc++) wf[nx][kc] = *(const short8*)(wrow + kc * 32 + kg);
            }
            #pragma unroll
            for (int kc = 0; kc < 4; kc++)
                accd[n0] = __builtin_amdgcn_mfma_f32_16x16x32_bf16(af2[kc], wf[cur][kc],
                                                                  accd[n0], 0, 0, 0);
        }
    }

    // ---- delta -> LDS bridge (MFMA layout writer, XOR-swizzled 16B chunks)
    #pragma unroll
    for (int n0 = 0; n0 < 8; n0++) {
        int c_w = wave * 32 + n0 * 4 + (fr >> 2);          // 16B chunk idx in row
        int pc  = c_w ^ ((c_w >> 3) & 7);                  // swizzle (involution)
        #pragma unroll
        for (int r = 0; r < 4; r++)
            Dls[((quad * 4 + r) << 10) + (pc << 2) + (fr & 3)] = accd[n0][r];
    }
    __syncthreads();                                   // bar4: delta ready

    // ---- residual + double-norm in LINEAR mapping -------------------------
    floatx4 dv4[8];
    float s1 = 0.0f, s2 = 0.0f;
    #pragma unroll
    for (int j = 0; j < 8; j++) {
        int c_r = j * 32 + l32;
        int pc  = c_r ^ ((c_r >> 3) & 7);
        floatx4 d = *(const floatx4*)&Dls[(lrow << 10) + (pc << 2)];
        dv4[j] = d;
        #pragma unroll
        for (int k = 0; k < 4; k++) {
            float od = ev4[j][k] + d[k];
            s1 += od; s2 += od * od;
        }
    }
    #pragma unroll
    for (int mm = 1; mm <= 16; mm <<= 1) {             // 32-lane row reduction
        s1 += __shfl_xor(s1, mm, 64);
        s2 += __shfl_xor(s2, mm, 64);
    }
    float m0 = s1 * (1.0f / DEMB);
    float iv = 1.0f / m0;
    float m  = m0 * iv;                                // mean(out/m0) ~ 1
    float st = s1 * iv;
    float var = (s2 * iv * iv - st * st * (1.0f / DEMB)) * (1.0f / (DEMB - 1));
    float isd = rsqrtf(var);

    // ---- final residual+norm; vectorized stores ---------------------------
    {
        float* eout = e + (size_t)(q0 + lrow) * DEMB + l32 * 4;
        __hip_bfloat16* ebout = ebf + (size_t)(q0 + lrow) * DEMB + l32 * 4;
        float* fout = last ? (out_final + (size_t)(q0 + lrow) * DEMB + l32 * 4) : nullptr;
        #pragma unroll
        for (int j = 0; j < 8; j++) {
            floatx4 res;
            #pragma unroll
            for (int k = 0; k < 4; k++) {
                float evv = ev4[j][k];
                float t = (evv + dv4[j][k]) * iv;
                res[k] = evv + (t - m) * isd + m;
            }
            if (last) {
                floatx4 ro = {res[0] * 0.125f, res[1] * 0.125f, res[2] * 0.125f, res[3] * 0.125f};
                *(floatx4*)(fout + j * 128) = ro;
            } else {
                *(floatx4*)(eout + j * 128) = res;
                union { __hip_bfloat16 h[4]; uint2 u; } p;
                #pragma unroll
                for (int k = 0; k < 4; k++) p.h[k] = __float2bfloat16(res[k]);
                *(uint2*)(ebout + j * 128) = p.u;
            }
        }
    }
}

extern "C" void kernel_launch(void* const* d_in, const int* in_sizes, int n_in,
                              void* d_out, int out_size, void* d_ws, size_t ws_size,
                              hipStream_t stream) {
    const float* x   = (const float*)d_in[0];
    const float* Wq  = (const float*)d_in[1];
    const float* Wk  = (const float*)d_in[2];
    const float* Wvd = (const float*)d_in[3];
    const float* Wvu = (const float*)d_in[4];

    char* ws = (char*)d_ws;
    float* e = (float*)ws;                                              // 16 MB
    __hip_bfloat16* ebf   = (__hip_bfloat16*)(ws + (16u << 20));        //  8 MB bf16 mirror of e
    __hip_bfloat16* Qb[2] = {(__hip_bfloat16*)(ws + (24u << 20)),
                             (__hip_bfloat16*)(ws + (27u << 20))};      //  1 MB each
    __hip_bfloat16* Kb[2] = {(__hip_bfloat16*)(ws + (25u << 20)),
                             (__hip_bfloat16*)(ws + (28u << 20))};
    __hip_bfloat16* Vt[2] = {(__hip_bfloat16*)(ws + (26u << 20)),
                             (__hip_bfloat16*)(ws + (29u << 20))};
    __hip_bfloat16* wqkvb = (__hip_bfloat16*)(ws + (30u << 20));        //  6 MB
    __hip_bfloat16* wvub  = (__hip_bfloat16*)(ws + (36u << 20));        //  2 MB  -> 38 MB

    pack_wqkv<<<NH * QKVW * DEMB / 8 / 256, 256, 0, stream>>>(Wq, Wk, Wvd, wqkvb);
    pack_wvu<<<NH * DEMB * DH / 8 / 256, 256, 0, stream>>>(Wvu, wvub);
    init_e<<<NTOK * DEMB / 4 / 256, 256, 0, stream>>>((const float4*)x, (float4*)e, ebf);

    // head-0 QKV from the x mirror
    qkv_gemm_mfma<<<dim3(QKVW / 32, NTOK / 64), 256, 0, stream>>>(
        ebf, wqkvb, Qb[0], Kb[0], Vt[0]);

    for (int h = 0; h < NH; h++) {
        int cur = h & 1, nxt = 1 - cur;
        attn_head<<<NTOK / QT, 512, 0, stream>>>(
            Qb[cur], Kb[cur], Vt[cur],
            ebf, wvub + (size_t)h * DEMB * DH, e,
            (h == NH - 1) ? (float*)d_out : nullptr);
        if (h + 1 < NH)   // de-fused next-head QKV (reads ebf written above)
            qkv_gemm_mfma<<<dim3(QKVW / 32, NTOK / 64), 256, 0, stream>>>(
                ebf, wqkvb + (size_t)(h + 1) * QKVW * DEMB,
                Qb[nxt], Kb[nxt], Vt[nxt]);
    }
}